// Round 8
// baseline (607.113 us; speedup 1.0000x reference)
//
#include <hip/hip_runtime.h>
#include <hip/hip_bf16.h>

#define BB   2
#define SS   2048
#define HH   2048
#define NHH  16
#define QLL  1536
#define KVLL 512
#define NOPE_D 128
#define ROPE_D 64
#define QKH_D  192
#define VD_D   128
#define MROWS  (BB*SS)           // 4096 token rows

typedef __attribute__((ext_vector_type(8))) short bf16x8;   // 8 bf16 (4 VGPRs)
typedef __attribute__((ext_vector_type(4))) float f32x4;    // MFMA accumulator

__device__ inline float bf2f(unsigned short u) {
    union { float f; unsigned int i; } v; v.i = ((unsigned int)u) << 16; return v.f;
}
__device__ inline unsigned short f2bf(float f) {
    union { float f; unsigned int u; } v; v.f = f;
    unsigned int r = v.u + 0x7fffu + ((v.u >> 16) & 1u);
    return (unsigned short)(r >> 16);
}

// async global->LDS, 16 B per lane.  LDS dest = wave-uniform base + lane*16.
__device__ __forceinline__ void gload_lds16(const ushort* g, ushort* l)
{
    __builtin_amdgcn_global_load_lds(
        (const __attribute__((address_space(1))) void*)(g),
        (__attribute__((address_space(3))) void*)(l), 16, 0, 0);
}

// ---------------------------------------------------------------------------
// One-launch f32 -> bf16 convert of all 6 tensors.
// ---------------------------------------------------------------------------
__global__ void conv6(const float* s0, ushort* d0, int n0,
                      const float* s1, ushort* d1, int n1,
                      const float* s2, ushort* d2, int n2,
                      const float* s3, ushort* d3, int n3,
                      const float* s4, ushort* d4, int n4,
                      const float* s5, ushort* d5, int n5)
{
    const int st = gridDim.x * 256;
    const int t0 = blockIdx.x * 256 + threadIdx.x;
    for (int i = t0; i < n0; i += st) { float4 v = ((const float4*)s0)[i]; ushort4 u; u.x=f2bf(v.x);u.y=f2bf(v.y);u.z=f2bf(v.z);u.w=f2bf(v.w); ((ushort4*)d0)[i]=u; }
    for (int i = t0; i < n1; i += st) { float4 v = ((const float4*)s1)[i]; ushort4 u; u.x=f2bf(v.x);u.y=f2bf(v.y);u.z=f2bf(v.z);u.w=f2bf(v.w); ((ushort4*)d1)[i]=u; }
    for (int i = t0; i < n2; i += st) { float4 v = ((const float4*)s2)[i]; ushort4 u; u.x=f2bf(v.x);u.y=f2bf(v.y);u.z=f2bf(v.z);u.w=f2bf(v.w); ((ushort4*)d2)[i]=u; }
    for (int i = t0; i < n3; i += st) { float4 v = ((const float4*)s3)[i]; ushort4 u; u.x=f2bf(v.x);u.y=f2bf(v.y);u.z=f2bf(v.z);u.w=f2bf(v.w); ((ushort4*)d3)[i]=u; }
    for (int i = t0; i < n4; i += st) { float4 v = ((const float4*)s4)[i]; ushort4 u; u.x=f2bf(v.x);u.y=f2bf(v.y);u.z=f2bf(v.z);u.w=f2bf(v.w); ((ushort4*)d4)[i]=u; }
    for (int i = t0; i < n5; i += st) { float4 v = ((const float4*)s5)[i]; ushort4 u; u.x=f2bf(v.x);u.y=f2bf(v.y);u.z=f2bf(v.z);u.w=f2bf(v.w); ((ushort4*)d5)[i]=u; }
}

// ---------------------------------------------------------------------------
// All-bf16 MFMA NT GEMM (as R7): 128x128 tile, BK=64, coalesced swizzled
// global_load_lds staging.  M mult of 128; N guarded; K mult of 64.
// ---------------------------------------------------------------------------
template<typename TC>
__launch_bounds__(256, 3)
__global__ void gemm_bf(const ushort* __restrict__ A, int lda, size_t Ab, size_t Ah,
                        const ushort* __restrict__ B, int ldb, size_t Bb, size_t Bh,
                        const float* __restrict__ bias,
                        TC* __restrict__ C, int ldc, size_t Cb, size_t Ch,
                        int M, int N, int K)
{
    __shared__ ushort As[128 * 64];
    __shared__ ushort Bs[128 * 64];
    const int z = blockIdx.z, bz = z >> 4, hz = z & 15;
    A += (size_t)bz * Ab + (size_t)hz * Ah;
    B += (size_t)bz * Bb + (size_t)hz * Bh;
    C += (size_t)bz * Cb + (size_t)hz * Ch;
    const int m0 = blockIdx.y * 128, n0 = blockIdx.x * 128;
    const int tid = threadIdx.x, w = tid >> 6, lane = tid & 63;
    const int l15 = lane & 15, q = lane >> 4;
    const int r7 = lane >> 3, c7 = lane & 7;
    const int xork = l15 & 7;

    f32x4 acc[4][4];
#pragma unroll
    for (int i = 0; i < 4; i++)
#pragma unroll
        for (int j = 0; j < 4; j++) acc[i][j] = (f32x4){0.f, 0.f, 0.f, 0.f};

    const int mrow = 64 * (w & 1) + l15;
    const int nrow = 64 * (w >> 1) + l15;

    for (int k0 = 0; k0 < K; k0 += 64) {
#pragma unroll
        for (int i = 0; i < 4; i++) {
            int g = 4 * w + i;
            int row = g * 8 + r7;
            int ch = c7 ^ r7;
            gload_lds16(A + (size_t)(m0 + row) * lda + k0 + ch * 8,
                        As + g * 512 + lane * 8);
            int rb = n0 + row; if (rb > N - 1) rb = N - 1;
            gload_lds16(B + (size_t)rb * ldb + k0 + ch * 8,
                        Bs + g * 512 + lane * 8);
        }
        __syncthreads();
#pragma unroll
        for (int ks = 0; ks < 2; ks++) {
            bf16x8 af[4], bf[4];
            const int chx = (ks * 4 + q) ^ xork;
#pragma unroll
            for (int mt = 0; mt < 4; mt++)
                af[mt] = *(const bf16x8*)(As + (mrow + 16 * mt) * 64 + chx * 8);
#pragma unroll
            for (int nt = 0; nt < 4; nt++)
                bf[nt] = *(const bf16x8*)(Bs + (nrow + 16 * nt) * 64 + chx * 8);
#pragma unroll
            for (int mt = 0; mt < 4; mt++)
#pragma unroll
                for (int nt = 0; nt < 4; nt++)
                    acc[mt][nt] = __builtin_amdgcn_mfma_f32_16x16x32_bf16(af[mt], bf[nt], acc[mt][nt], 0, 0, 0);
        }
        __syncthreads();
    }

#pragma unroll
    for (int nt = 0; nt < 4; nt++) {
        int n = n0 + nrow + 16 * nt;
        if (n >= N) continue;
        float bv = bias ? bias[n] : 0.f;
#pragma unroll
        for (int mt = 0; mt < 4; mt++) {
#pragma unroll
            for (int r = 0; r < 4; r++) {
                int m = m0 + 64 * (w & 1) + 16 * mt + 4 * q + r;
                float v = acc[mt][nt][r] + bv;
                if constexpr (sizeof(TC) == 2) C[(size_t)m * ldc + n] = f2bf(v);
                else                           C[(size_t)m * ldc + n] = v;
            }
        }
    }
}

// ---------------------------------------------------------------------------
// RMSNorm bf16 in -> bf16 out, in place.  One 256-thread block per row.
// ---------------------------------------------------------------------------
__launch_bounds__(256)
__global__ void rmsnorm_bf16(ushort* __restrict__ x, const float* __restrict__ w, int width)
{
    ushort* xr = x + (size_t)blockIdx.x * width;
    float ss = 0.f;
    for (int i = threadIdx.x; i < width; i += 256) { float v = bf2f(xr[i]); ss += v * v; }
    __shared__ float red[256];
    red[threadIdx.x] = ss; __syncthreads();
    for (int off = 128; off > 0; off >>= 1) {
        if (threadIdx.x < off) red[threadIdx.x] += red[threadIdx.x + off];
        __syncthreads();
    }
    float r = rsqrtf(red[0] / (float)width + 1e-6f);
    for (int i = threadIdx.x; i < width; i += 256)
        xr[i] = f2bf(w[i] * bf2f(xr[i]) * r);
}

__device__ inline float rope_val(float xj, float xo, int j, int s)
{
    int i = j & 31;
    float freq = powf(10000.f, -(float)i / 32.f);
    float a = (float)s * freq;
    float sn, cs; sincosf(a, &sn, &cs);
    float other = (j < 32) ? -xo : xo;
    return xj * cs + other * sn;
}

// kv finalize: rms_norm latent 512 + rope pe 64, bf16 in -> kvbf bf16
__launch_bounds__(256)
__global__ void finalize_kv(const ushort* __restrict__ kvf, const float* __restrict__ w,
                            ushort* __restrict__ kvbf)
{
    int m = blockIdx.x, s = m & (SS - 1);
    const ushort* xr = kvf + (size_t)m * 576;
    float ss = 0.f;
    for (int i = threadIdx.x; i < 512; i += 256) { float v = bf2f(xr[i]); ss += v * v; }
    __shared__ float red[256];
    red[threadIdx.x] = ss; __syncthreads();
    for (int off = 128; off > 0; off >>= 1) {
        if (threadIdx.x < off) red[threadIdx.x] += red[threadIdx.x + off];
        __syncthreads();
    }
    float r = rsqrtf(red[0] / 512.f + 1e-6f);
    for (int i = threadIdx.x; i < 512; i += 256)
        kvbf[(size_t)m * 576 + i] = f2bf(w[i] * bf2f(xr[i]) * r);
    if (threadIdx.x < 64) {
        int j = threadIdx.x;
        float xj = bf2f(xr[512 + j]), xo = bf2f(xr[512 + (j ^ 32)]);
        kvbf[(size_t)m * 576 + 512 + j] = f2bf(rope_val(xj, xo, j, s));
    }
}

// RoPE q_pe in place on qbuf bf16.  grid (4096,4) x 256; wave owns one head.
__global__ void rope_q_kernel(ushort* __restrict__ qbuf)
{
    int m = blockIdx.x, s = m & (SS - 1);
    int w = threadIdx.x >> 6, j = threadIdx.x & 63;
    int h = blockIdx.y * 4 + w;
    ushort* p = qbuf + (size_t)m * 3072 + h * QKH_D + NOPE_D;
    float xj = bf2f(p[j]);
    float xo = bf2f(p[j ^ 32]);
    p[j] = f2bf(rope_val(xj, xo, j, s));
}

// ---------------------------------------------------------------------------
// MFMA flash attention, split-K (R7 job tables), wave-autonomous PV:
// wave w owns q-rows [s0+16w,+16) end-to-end.  Scores use the shared K-tile
// (Kf nope 128 dims + k_pe 64 dims staged from kvbf); softmax is intra-wave;
// P goes through a WAVE-PRIVATE LDS slab (no barrier); PV reads V^T B-frags
// from global VT.  2 barriers per step (protect shared Kt only).
// ---------------------------------------------------------------------------
#define SCL  0.10411760f  // (1/sqrt(192)) * log2(e)
#define PTL  72
#define NJOB 45

__constant__ unsigned char JQT[NJOB] = {18,17,16,19,20,21,22,23,24,25,26,27,28,29,30,31,15,31,14,30,13,29,12,28,11,27,10,26,9,25,8,24,7,23,6,22,5,21,4,20,3,19,2,1,0};
__constant__ unsigned char JT0[NJOB] = { 0, 0, 0, 0, 0, 0, 0, 0, 0, 0, 0, 0, 0, 0, 0, 0, 0,16, 0,16, 0,16, 0,16, 0,16, 0,16, 0,16, 0,16, 0,16, 0,16, 0,16, 0,16, 0,16, 0, 0, 0};
__constant__ unsigned char JT1[NJOB] = {19,18,17,16,16,16,16,16,16,16,16,16,16,16,16,16,16,32,15,31,14,30,13,29,12,28,11,27,10,26, 9,25, 8,24, 7,23, 6,22, 5,21, 4,20, 3, 2, 1};

__device__ __forceinline__ int ktidx(int row, int ch) {
    return (((ch >> 3) << 3) + (row >> 3)) * 512 + (row & 7) * 64 + (((ch & 7) ^ (row & 7)) << 3);
}

__launch_bounds__(256, 4)
__global__ void attn_mfma(const ushort* __restrict__ qbuf, const ushort* __restrict__ Kf,
                          const ushort* __restrict__ kvbf, const ushort* __restrict__ VT,
                          const int* __restrict__ mask, ushort* __restrict__ o_heads,
                          ushort* __restrict__ Opart, float2* __restrict__ mlbuf)
{
    __shared__ ushort Kt[24 * 512];      // 24,576 B shared K-tile
    __shared__ ushort Pt[4 * 16 * PTL];  //  9,216 B wave-private P slabs

    const int tid = threadIdx.x, w = tid >> 6, lane = tid & 63;
    const int l15 = lane & 15, q = lane >> 4;
    const int r7 = lane >> 3, c7 = lane & 7;

    const int job = blockIdx.x >> 5, bh = blockIdx.x & 31;
    const int b = bh >> 4, h = bh & 15;
    const int qt = JQT[job], t0s = JT0[job], t1s = JT1[job];
    const int s0 = qt * 64;
    const bool partial = (t0s != 0) | (t1s != qt + 1);

    const ushort* Kf_bh = Kf + (size_t)bh * SS * NOPE_D;
    const ushort* VT_bh = VT + (size_t)bh * VD_D * SS;
    const ushort* kpe_b = kvbf + (size_t)b * SS * 576 + 512;
    const int* mrow = mask + b * SS;
    ushort* Ptw = Pt + w * 16 * PTL;

    // Q A-frags: rows s0+16w..+15, 6 k-chunks of 32 over 192 dims
    bf16x8 qf[6];
    {
        const ushort* qbase = qbuf + ((size_t)(b * SS) + s0 + 16 * w + l15) * 3072 + h * QKH_D + q * 8;
#pragma unroll
        for (int k = 0; k < 6; k++) qf[k] = *(const bf16x8*)(qbase + k * 32);
    }

    f32x4 Oacc[8];
#pragma unroll
    for (int nt = 0; nt < 8; nt++) Oacc[nt] = (f32x4){0.f, 0.f, 0.f, 0.f};
    float m_i[4] = {-3e38f, -3e38f, -3e38f, -3e38f};
    float l_i[4] = {0.f, 0.f, 0.f, 0.f};

    for (int st = t0s; st < t1s; st++) {
        const int t0 = st * 64;
        // ---- stage K-tile: chunks 0..15 from Kf (nope), 16..23 from kvbf pe ----
#pragma unroll
        for (int i = 0; i < 6; i++) {
            int g = 6 * w + i;                 // 0..23
            int rg = g & 7, cg = g >> 3;
            int row = rg * 8 + r7;
            int chl = c7 ^ r7;                 // chunk-in-group
            const ushort* src = (cg < 2)
                ? Kf_bh + (size_t)(t0 + row) * NOPE_D + (cg * 8 + chl) * 8
                : kpe_b + (size_t)(t0 + row) * 576 + chl * 8;
            gload_lds16(src, Kt + g * 512 + lane * 8);
        }
        __syncthreads();
        // ---- scores S(16 x 64) for my rows ----
        f32x4 sa[4];
#pragma unroll
        for (int c = 0; c < 4; c++) sa[c] = (f32x4){0.f, 0.f, 0.f, 0.f};
#pragma unroll
        for (int k = 0; k < 6; k++) {
#pragma unroll
            for (int c = 0; c < 4; c++) {
                bf16x8 kb = *(const bf16x8*)(Kt + ktidx(16 * c + l15, 4 * k + q));
                sa[c] = __builtin_amdgcn_mfma_f32_16x16x32_bf16(qf[k], kb, sa[c], 0, 0, 0);
            }
        }
        // ---- intra-wave online softmax; P -> wave-private LDS ----
        int mv[4];
#pragma unroll
        for (int c = 0; c < 4; c++) mv[c] = mrow[t0 + 16 * c + l15];
        float alpha[4];
#pragma unroll
        for (int r = 0; r < 4; r++) {
            const int srow = s0 + 16 * w + 4 * q + r;
            float s_c[4];
#pragma unroll
            for (int c = 0; c < 4; c++) {
                s_c[c] = sa[c][r] * SCL;
                int col = t0 + 16 * c + l15;
                if (col > srow || mv[c] == 0) s_c[c] = -1e30f;
            }
            float mx = fmaxf(fmaxf(s_c[0], s_c[1]), fmaxf(s_c[2], s_c[3]));
            mx = fmaxf(mx, __shfl_xor(mx, 1)); mx = fmaxf(mx, __shfl_xor(mx, 2));
            mx = fmaxf(mx, __shfl_xor(mx, 4)); mx = fmaxf(mx, __shfl_xor(mx, 8));
            float mn = fmaxf(m_i[r], mx);
            alpha[r] = exp2f(m_i[r] - mn);
            m_i[r] = mn;
            float ps = 0.f;
#pragma unroll
            for (int c = 0; c < 4; c++) {
                float pc = (s_c[c] <= -1e29f) ? 0.f : exp2f(s_c[c] - mn);
                ps += pc;
                Ptw[(4 * q + r) * PTL + 16 * c + l15] = f2bf(pc);
            }
            ps += __shfl_xor(ps, 1); ps += __shfl_xor(ps, 2);
            ps += __shfl_xor(ps, 4); ps += __shfl_xor(ps, 8);
            l_i[r] = l_i[r] * alpha[r] + ps;
        }
        // ---- rescale O (rows match softmax rows; intra-wave) ----
#pragma unroll
        for (int nt = 0; nt < 8; nt++) {
            Oacc[nt][0] *= alpha[0]; Oacc[nt][1] *= alpha[1];
            Oacc[nt][2] *= alpha[2]; Oacc[nt][3] *= alpha[3];
        }
        // ---- PV: O(16 s x 128 d) += P(16x64) @ V(64x128), no barrier ----
        bf16x8 pa[2];
#pragma unroll
        for (int kt = 0; kt < 2; kt++)
            pa[kt] = *(const bf16x8*)(Ptw + l15 * PTL + kt * 32 + q * 8);
#pragma unroll
        for (int nt = 0; nt < 8; nt++) {
            const ushort* vb = VT_bh + (size_t)(16 * nt + l15) * SS + t0 + q * 8;
            bf16x8 v0 = *(const bf16x8*)(vb);
            bf16x8 v1 = *(const bf16x8*)(vb + 32);
            Oacc[nt] = __builtin_amdgcn_mfma_f32_16x16x32_bf16(pa[0], v0, Oacc[nt], 0, 0, 0);
            Oacc[nt] = __builtin_amdgcn_mfma_f32_16x16x32_bf16(pa[1], v1, Oacc[nt], 0, 0, 0);
        }
        __syncthreads();   // protect Kt for next step's staging
    }

    // ---- epilogue (all intra-wave) ----
    float lv[4];
#pragma unroll
    for (int r = 0; r < 4; r++) lv[r] = (l_i[r] > 0.f) ? 1.f / l_i[r] : 0.f;

    if (!partial) {
#pragma unroll
        for (int nt = 0; nt < 8; nt++) {
            int d = 16 * nt + l15;
#pragma unroll
            for (int r = 0; r < 4; r++) {
                int s = s0 + 16 * w + 4 * q + r;
                o_heads[(size_t)(b * SS + s) * 2048 + h * VD_D + d] = f2bf(Oacc[nt][r] * lv[r]);
            }
        }
    } else {
        const int sp = (t0s != 0);
        const int p = bh * 26 + (qt - 19) * 2 + sp;
#pragma unroll
        for (int nt = 0; nt < 8; nt++) {
            int d = 16 * nt + l15;
#pragma unroll
            for (int r = 0; r < 4; r++) {
                int rl = 16 * w + 4 * q + r;
                Opart[((size_t)p * 64 + rl) * 128 + d] = f2bf(Oacc[nt][r] * lv[r]);
            }
        }
        if (l15 == 0) {
#pragma unroll
            for (int r = 0; r < 4; r++)
                mlbuf[p * 64 + 16 * w + 4 * q + r] = make_float2(m_i[r], l_i[r]);
        }
    }
}

// ---------------------------------------------------------------------------
// Merge span0/span1 partials for qt>=19.  grid 416 (= 32bh x 13qt) x 256.
// ---------------------------------------------------------------------------
__launch_bounds__(256)
__global__ void attn_merge(const ushort* __restrict__ Opart, const float2* __restrict__ mlbuf,
                           ushort* __restrict__ o_heads)
{
    int bh = blockIdx.x & 31, qi = blockIdx.x >> 5;
    int b = bh >> 4, h = bh & 15;
    int qt = 19 + qi;
    int t = threadIdx.x;
    int row = t >> 2, dbase = (t & 3) * 32;
    int p0 = bh * 26 + qi * 2, p1 = p0 + 1;
    float2 ml0 = mlbuf[p0 * 64 + row], ml1 = mlbuf[p1 * 64 + row];
    float M = fmaxf(ml0.x, ml1.x);
    float w0 = (ml0.y > 0.f) ? exp2f(ml0.x - M) * ml0.y : 0.f;
    float w1 = (ml1.y > 0.f) ? exp2f(ml1.x - M) * ml1.y : 0.f;
    float den = w0 + w1;
    float inv = (den > 0.f) ? 1.f / den : 0.f;
    w0 *= inv; w1 *= inv;
    int s = qt * 64 + row;
    const ushort* O0 = Opart + ((size_t)p0 * 64 + row) * 128 + dbase;
    const ushort* O1 = Opart + ((size_t)p1 * 64 + row) * 128 + dbase;
    ushort* dst = o_heads + (size_t)(b * SS + s) * 2048 + h * VD_D + dbase;
#pragma unroll
    for (int c = 0; c < 32; c += 8) {
        bf16x8 a = *(const bf16x8*)(O0 + c);
        bf16x8 bb = *(const bf16x8*)(O1 + c);
        bf16x8 o;
#pragma unroll
        for (int j = 0; j < 8; j++)
            o[j] = (short)f2bf(w0 * bf2f((unsigned short)a[j]) + w1 * bf2f((unsigned short)bb[j]));
        *(bf16x8*)(dst + c) = o;
    }
}

extern "C" void kernel_launch(void* const* d_in, const int* in_sizes, int n_in,
                              void* d_out, int out_size, void* d_ws, size_t ws_size,
                              hipStream_t stream)
{
    const float* x        = (const float*)d_in[0];
    const int*   mask     = (const int*)d_in[1];
    const float* wq_a_w   = (const float*)d_in[2];
    const float* wq_a_b   = (const float*)d_in[3];
    const float* q_norm_w = (const float*)d_in[4];
    const float* wq_b_w   = (const float*)d_in[5];
    const float* wq_b_b   = (const float*)d_in[6];
    const float* wkv_a_w  = (const float*)d_in[7];
    const float* wkv_a_b  = (const float*)d_in[8];
    const float* kv_norm_w= (const float*)d_in[9];
    const float* wkv_b_w  = (const float*)d_in[10];
    const float* wo_w     = (const float*)d_in[11];
    const float* wo_b     = (const float*)d_in[12];
    float* out = (float*)d_out;

    // Workspace (peak 102,662,144 B; <= 108.5 MB proven):
    //  wo_bf     [0, 8388608)                                  (ph0-12)
    //  qbuf      [8388608, 33554432)                           (ph3-10)
    //  Kf region [33554432, 50331648): wq_b_bf(0-3)@33554432,
    //            wq_a_bf(0-1)@42991616, kvfull_bf(4-5)@42991616 -> Kf(7-10)
    //  VT region [50331648, 67108864): x_bf(0-4) -> VT(9-10)
    //  o_heads   [67108864, 83886080): q_a_bf(1-3)@67108864,
    //            wkv_a_bf(0-4)@79691776 -> o_heads(10-12)
    //  Opart     [83886080, 97517568): wkv_b_bf(0-9)@83886080 -> Opart(10-11)
    //  mlbuf     [97517568, 97943552)                          (10-11)
    //  kvbf      [97943552, 102662144)                         (5-10)
    char* W = (char*)d_ws;
    ushort* wo_bf    = (ushort*)(W + 0);
    ushort* qbuf     = (ushort*)(W + 8388608);
    ushort* wq_b_bf  = (ushort*)(W + 33554432);
    ushort* Kf       = (ushort*)(W + 33554432);
    ushort* wq_a_bf  = (ushort*)(W + 42991616);
    ushort* kvfull_bf= (ushort*)(W + 42991616);
    ushort* x_bf     = (ushort*)(W + 50331648);
    ushort* VT       = (ushort*)(W + 50331648);
    ushort* q_a_bf   = (ushort*)(W + 67108864);
    ushort* o_heads  = (ushort*)(W + 67108864);
    ushort* wkv_a_bf = (ushort*)(W + 79691776);
    ushort* wkv_b_bf = (ushort*)(W + 83886080);
    ushort* Opart    = (ushort*)(W + 83886080);
    float2* mlbuf    = (float2*)(W + 97517568);
    ushort* kvbf     = (ushort*)(W + 97943552);

    // 0. all f32->bf16 converts, one launch
    conv6<<<4096, 256, 0, stream>>>(
        x, x_bf, MROWS * HH / 4,
        wq_a_w, wq_a_bf, QLL * HH / 4,
        wq_b_w, wq_b_bf, 3072 * QLL / 4,
        wkv_a_w, wkv_a_bf, 576 * HH / 4,
        wkv_b_w, wkv_b_bf, NHH * 256 * 512 / 4,
        wo_w, wo_bf, HH * 2048 / 4);

    // 1. q_a = x @ wq_a^T + b  -> bf16
    gemm_bf<ushort><<<dim3(QLL/128, MROWS/128, 1), 256, 0, stream>>>(
        x_bf, HH, 0, 0, wq_a_bf, HH, 0, 0, wq_a_b, q_a_bf, QLL, 0, 0, MROWS, QLL, HH);
    // 2. rms_norm in place (bf16)
    rmsnorm_bf16<<<MROWS, 256, 0, stream>>>(q_a_bf, q_norm_w, QLL);
    // 3. q = q_a @ wq_b^T + b -> qbuf bf16
    gemm_bf<ushort><<<dim3(3072/128, MROWS/128, 1), 256, 0, stream>>>(
        q_a_bf, QLL, 0, 0, wq_b_bf, QLL, 0, 0, wq_b_b, qbuf, 3072, 0, 0, MROWS, 3072, QLL);
    // 4. kv_full = x @ wkv_a^T + b -> bf16 (N=576 guarded)
    gemm_bf<ushort><<<dim3(5, MROWS/128, 1), 256, 0, stream>>>(
        x_bf, HH, 0, 0, wkv_a_bf, HH, 0, 0, wkv_a_b, kvfull_bf, 576, 0, 0, MROWS, 576, HH);
    // 5. finalize kv (rms + rope) -> kvbf
    finalize_kv<<<MROWS, 256, 0, stream>>>(kvfull_bf, kv_norm_w, kvbf);
    // 6. rope q_pe in place on qbuf
    rope_q_kernel<<<dim3(MROWS, 4), 256, 0, stream>>>(qbuf);
    // 7. Kf[b,h] = kv_lat @ W_UK[h]^T  (nope only; M=2048,N=128,K=512, z=32)
    gemm_bf<ushort><<<dim3(1, SS/128, 32), 256, 0, stream>>>(
        kvbf, 576, (size_t)SS * 576, 0,
        wkv_b_bf, 512, 0, (size_t)256 * 512,
        nullptr, Kf, NOPE_D, (size_t)NHH * SS * NOPE_D, (size_t)SS * NOPE_D,
        SS, NOPE_D, 512);
    // 9. VT[b,h] = W_UV[h] @ kv_lat^T  (M=128,N=2048,K=512, z=32)
    gemm_bf<ushort><<<dim3(SS/128, 1, 32), 256, 0, stream>>>(
        wkv_b_bf + (size_t)128 * 512, 512, 0, (size_t)256 * 512,
        kvbf, 576, (size_t)SS * 576, 0,
        nullptr, VT, SS, (size_t)NHH * VD_D * SS, (size_t)VD_D * SS,
        VD_D, SS, 512);
    // 10. split-K MFMA flash attention (1440 blocks) + merge
    attn_mfma<<<NJOB * 32, 256, 0, stream>>>(qbuf, Kf, kvbf, VT, mask, o_heads, Opart, mlbuf);
    attn_merge<<<13 * 32, 256, 0, stream>>>(Opart, mlbuf, o_heads);
    // 12. out = o_heads @ wo^T + b
    gemm_bf<float><<<dim3(HH/128, MROWS/128, 1), 256, 0, stream>>>(
        o_heads, NHH * VD_D, 0, 0, wo_bf, NHH * VD_D, 0, 0, wo_b, out, HH, 0, 0,
        MROWS, HH, NHH * VD_D);
}

// Round 9
// 479.204 us; speedup vs baseline: 1.2669x; 1.2669x over previous
//
#include <hip/hip_runtime.h>
#include <hip/hip_bf16.h>

#define BB   2
#define SS   2048
#define HH   2048
#define NHH  16
#define QLL  1536
#define KVLL 512
#define NOPE_D 128
#define ROPE_D 64
#define QKH_D  192
#define VD_D   128
#define MROWS  (BB*SS)           // 4096 token rows

typedef __attribute__((ext_vector_type(8))) short bf16x8;   // 8 bf16 (4 VGPRs)
typedef __attribute__((ext_vector_type(4))) float f32x4;    // MFMA accumulator

__device__ inline float bf2f(unsigned short u) {
    union { float f; unsigned int i; } v; v.i = ((unsigned int)u) << 16; return v.f;
}
__device__ inline unsigned short f2bf(float f) {
    union { float f; unsigned int u; } v; v.f = f;
    unsigned int r = v.u + 0x7fffu + ((v.u >> 16) & 1u);
    return (unsigned short)(r >> 16);
}

// async global->LDS, 16 B per lane.  LDS dest = wave-uniform base + lane*16.
__device__ __forceinline__ void gload_lds16(const ushort* g, ushort* l)
{
    __builtin_amdgcn_global_load_lds(
        (const __attribute__((address_space(1))) void*)(g),
        (__attribute__((address_space(3))) void*)(l), 16, 0, 0);
}

// ---------------------------------------------------------------------------
// One-launch f32 -> bf16 convert of all 6 tensors.
// ---------------------------------------------------------------------------
__global__ void conv6(const float* s0, ushort* d0, int n0,
                      const float* s1, ushort* d1, int n1,
                      const float* s2, ushort* d2, int n2,
                      const float* s3, ushort* d3, int n3,
                      const float* s4, ushort* d4, int n4,
                      const float* s5, ushort* d5, int n5)
{
    const int st = gridDim.x * 256;
    const int t0 = blockIdx.x * 256 + threadIdx.x;
    for (int i = t0; i < n0; i += st) { float4 v = ((const float4*)s0)[i]; ushort4 u; u.x=f2bf(v.x);u.y=f2bf(v.y);u.z=f2bf(v.z);u.w=f2bf(v.w); ((ushort4*)d0)[i]=u; }
    for (int i = t0; i < n1; i += st) { float4 v = ((const float4*)s1)[i]; ushort4 u; u.x=f2bf(v.x);u.y=f2bf(v.y);u.z=f2bf(v.z);u.w=f2bf(v.w); ((ushort4*)d1)[i]=u; }
    for (int i = t0; i < n2; i += st) { float4 v = ((const float4*)s2)[i]; ushort4 u; u.x=f2bf(v.x);u.y=f2bf(v.y);u.z=f2bf(v.z);u.w=f2bf(v.w); ((ushort4*)d2)[i]=u; }
    for (int i = t0; i < n3; i += st) { float4 v = ((const float4*)s3)[i]; ushort4 u; u.x=f2bf(v.x);u.y=f2bf(v.y);u.z=f2bf(v.z);u.w=f2bf(v.w); ((ushort4*)d3)[i]=u; }
    for (int i = t0; i < n4; i += st) { float4 v = ((const float4*)s4)[i]; ushort4 u; u.x=f2bf(v.x);u.y=f2bf(v.y);u.z=f2bf(v.z);u.w=f2bf(v.w); ((ushort4*)d4)[i]=u; }
    for (int i = t0; i < n5; i += st) { float4 v = ((const float4*)s5)[i]; ushort4 u; u.x=f2bf(v.x);u.y=f2bf(v.y);u.z=f2bf(v.z);u.w=f2bf(v.w); ((ushort4*)d5)[i]=u; }
}

// ---------------------------------------------------------------------------
// All-bf16 MFMA NT GEMM: 128x128 tile, BK=64, coalesced swizzled
// global_load_lds staging.  M mult of 128; N guarded; K mult of 64.
// ---------------------------------------------------------------------------
template<typename TC>
__launch_bounds__(256, 3)
__global__ void gemm_bf(const ushort* __restrict__ A, int lda, size_t Ab, size_t Ah,
                        const ushort* __restrict__ B, int ldb, size_t Bb, size_t Bh,
                        const float* __restrict__ bias,
                        TC* __restrict__ C, int ldc, size_t Cb, size_t Ch,
                        int M, int N, int K)
{
    __shared__ ushort As[128 * 64];
    __shared__ ushort Bs[128 * 64];
    const int z = blockIdx.z, bz = z >> 4, hz = z & 15;
    A += (size_t)bz * Ab + (size_t)hz * Ah;
    B += (size_t)bz * Bb + (size_t)hz * Bh;
    C += (size_t)bz * Cb + (size_t)hz * Ch;
    const int m0 = blockIdx.y * 128, n0 = blockIdx.x * 128;
    const int tid = threadIdx.x, w = tid >> 6, lane = tid & 63;
    const int l15 = lane & 15, q = lane >> 4;
    const int r7 = lane >> 3, c7 = lane & 7;
    const int xork = l15 & 7;

    f32x4 acc[4][4];
#pragma unroll
    for (int i = 0; i < 4; i++)
#pragma unroll
        for (int j = 0; j < 4; j++) acc[i][j] = (f32x4){0.f, 0.f, 0.f, 0.f};

    const int mrow = 64 * (w & 1) + l15;
    const int nrow = 64 * (w >> 1) + l15;

    for (int k0 = 0; k0 < K; k0 += 64) {
#pragma unroll
        for (int i = 0; i < 4; i++) {
            int g = 4 * w + i;
            int row = g * 8 + r7;
            int ch = c7 ^ r7;
            gload_lds16(A + (size_t)(m0 + row) * lda + k0 + ch * 8,
                        As + g * 512 + lane * 8);
            int rb = n0 + row; if (rb > N - 1) rb = N - 1;
            gload_lds16(B + (size_t)rb * ldb + k0 + ch * 8,
                        Bs + g * 512 + lane * 8);
        }
        __syncthreads();
#pragma unroll
        for (int ks = 0; ks < 2; ks++) {
            bf16x8 af[4], bf[4];
            const int chx = (ks * 4 + q) ^ xork;
#pragma unroll
            for (int mt = 0; mt < 4; mt++)
                af[mt] = *(const bf16x8*)(As + (mrow + 16 * mt) * 64 + chx * 8);
#pragma unroll
            for (int nt = 0; nt < 4; nt++)
                bf[nt] = *(const bf16x8*)(Bs + (nrow + 16 * nt) * 64 + chx * 8);
#pragma unroll
            for (int mt = 0; mt < 4; mt++)
#pragma unroll
                for (int nt = 0; nt < 4; nt++)
                    acc[mt][nt] = __builtin_amdgcn_mfma_f32_16x16x32_bf16(af[mt], bf[nt], acc[mt][nt], 0, 0, 0);
        }
        __syncthreads();
    }

#pragma unroll
    for (int nt = 0; nt < 4; nt++) {
        int n = n0 + nrow + 16 * nt;
        if (n >= N) continue;
        float bv = bias ? bias[n] : 0.f;
#pragma unroll
        for (int mt = 0; mt < 4; mt++) {
#pragma unroll
            for (int r = 0; r < 4; r++) {
                int m = m0 + 64 * (w & 1) + 16 * mt + 4 * q + r;
                float v = acc[mt][nt][r] + bv;
                if constexpr (sizeof(TC) == 2) C[(size_t)m * ldc + n] = f2bf(v);
                else                           C[(size_t)m * ldc + n] = v;
            }
        }
    }
}

// ---------------------------------------------------------------------------
// RMSNorm bf16 in-place.  One 256-thread block per row.
// ---------------------------------------------------------------------------
__launch_bounds__(256)
__global__ void rmsnorm_bf16(ushort* __restrict__ x, const float* __restrict__ w, int width)
{
    ushort* xr = x + (size_t)blockIdx.x * width;
    float ss = 0.f;
    for (int i = threadIdx.x; i < width; i += 256) { float v = bf2f(xr[i]); ss += v * v; }
    __shared__ float red[256];
    red[threadIdx.x] = ss; __syncthreads();
    for (int off = 128; off > 0; off >>= 1) {
        if (threadIdx.x < off) red[threadIdx.x] += red[threadIdx.x + off];
        __syncthreads();
    }
    float r = rsqrtf(red[0] / (float)width + 1e-6f);
    for (int i = threadIdx.x; i < width; i += 256)
        xr[i] = f2bf(w[i] * bf2f(xr[i]) * r);
}

__device__ inline float rope_val(float xj, float xo, int j, int s)
{
    int i = j & 31;
    float freq = powf(10000.f, -(float)i / 32.f);
    float a = (float)s * freq;
    float sn, cs; sincosf(a, &sn, &cs);
    float other = (j < 32) ? -xo : xo;
    return xj * cs + other * sn;
}

// kv finalize: rms_norm latent 512 + rope pe 64, bf16 in -> kvbf bf16
__launch_bounds__(256)
__global__ void finalize_kv(const ushort* __restrict__ kvf, const float* __restrict__ w,
                            ushort* __restrict__ kvbf)
{
    int m = blockIdx.x, s = m & (SS - 1);
    const ushort* xr = kvf + (size_t)m * 576;
    float ss = 0.f;
    for (int i = threadIdx.x; i < 512; i += 256) { float v = bf2f(xr[i]); ss += v * v; }
    __shared__ float red[256];
    red[threadIdx.x] = ss; __syncthreads();
    for (int off = 128; off > 0; off >>= 1) {
        if (threadIdx.x < off) red[threadIdx.x] += red[threadIdx.x + off];
        __syncthreads();
    }
    float r = rsqrtf(red[0] / 512.f + 1e-6f);
    for (int i = threadIdx.x; i < 512; i += 256)
        kvbf[(size_t)m * 576 + i] = f2bf(w[i] * bf2f(xr[i]) * r);
    if (threadIdx.x < 64) {
        int j = threadIdx.x;
        float xj = bf2f(xr[512 + j]), xo = bf2f(xr[512 + (j ^ 32)]);
        kvbf[(size_t)m * 576 + 512 + j] = f2bf(rope_val(xj, xo, j, s));
    }
}

// RoPE q_pe in place on qbuf bf16.  grid (4096,4) x 256; wave owns one head.
__global__ void rope_q_kernel(ushort* __restrict__ qbuf)
{
    int m = blockIdx.x, s = m & (SS - 1);
    int w = threadIdx.x >> 6, j = threadIdx.x & 63;
    int h = blockIdx.y * 4 + w;
    ushort* p = qbuf + (size_t)m * 3072 + h * QKH_D + NOPE_D;
    float xj = bf2f(p[j]);
    float xo = bf2f(p[j ^ 32]);
    p[j] = f2bf(rope_val(xj, xo, j, s));
}

// ---------------------------------------------------------------------------
// MFMA flash attention, TRANSPOSED dataflow:
//   S^T = K·Q^T  (s on lane axis, t on register axis)
//   -> softmax: in-register reduce over 16 t + 2 shfl_xor (16,32); m/l/alpha
//      are one scalar per lane.
//   O^T = V^T·P^T: V^T tile staged in shared LDS (once per step); P^T via
//      wave-private LDS slab (no barrier).  2 barriers/step (Kt+Vt).
// Split-K job tables from R7.  Wave w owns q-rows [s0+16w,+16).
// ---------------------------------------------------------------------------
#define SCL  0.10411760f  // (1/sqrt(192)) * log2(e)
#define PTL  72
#define NJOB 45

__constant__ unsigned char JQT[NJOB] = {18,17,16,19,20,21,22,23,24,25,26,27,28,29,30,31,15,31,14,30,13,29,12,28,11,27,10,26,9,25,8,24,7,23,6,22,5,21,4,20,3,19,2,1,0};
__constant__ unsigned char JT0[NJOB] = { 0, 0, 0, 0, 0, 0, 0, 0, 0, 0, 0, 0, 0, 0, 0, 0, 0,16, 0,16, 0,16, 0,16, 0,16, 0,16, 0,16, 0,16, 0,16, 0,16, 0,16, 0,16, 0,16, 0, 0, 0};
__constant__ unsigned char JT1[NJOB] = {19,18,17,16,16,16,16,16,16,16,16,16,16,16,16,16,16,32,15,31,14,30,13,29,12,28,11,27,10,26, 9,25, 8,24, 7,23, 6,22, 5,21, 4,20, 3, 2, 1};

__device__ __forceinline__ int ktidx(int row, int ch) {
    return (((ch >> 3) << 3) + (row >> 3)) * 512 + (row & 7) * 64 + (((ch & 7) ^ (row & 7)) << 3);
}
// Vt: 16 groups of 8 d-rows; slot swizzle chunk^(d&7)
__device__ __forceinline__ int vtidx(int d, int ch) {
    return (d >> 3) * 512 + (d & 7) * 64 + ((ch ^ (d & 7)) << 3);
}

__launch_bounds__(256, 3)
__global__ void attn_mfma(const ushort* __restrict__ qbuf, const ushort* __restrict__ Kf,
                          const ushort* __restrict__ kvbf, const ushort* __restrict__ VT,
                          const int* __restrict__ mask, ushort* __restrict__ o_heads,
                          ushort* __restrict__ Opart, float2* __restrict__ mlbuf)
{
    __shared__ ushort Kt[24 * 512];      // 24,576 B shared K-tile (64 t x 192)
    __shared__ ushort Vt[16 * 512];      // 16,384 B shared V^T tile (128 d x 64 t)
    __shared__ ushort Pt[4 * 16 * PTL];  //  9,216 B wave-private P^T slabs

    const int tid = threadIdx.x, w = tid >> 6, lane = tid & 63;
    const int l15 = lane & 15, q = lane >> 4;
    const int r7 = lane >> 3, c7 = lane & 7;

    const int job = blockIdx.x >> 5, bh = blockIdx.x & 31;
    const int b = bh >> 4, h = bh & 15;
    const int qt = JQT[job], t0s = JT0[job], t1s = JT1[job];
    const int s0 = qt * 64;
    const bool partial = (t0s != 0) | (t1s != qt + 1);

    const ushort* Kf_bh = Kf + (size_t)bh * SS * NOPE_D;
    const ushort* VT_bh = VT + (size_t)bh * VD_D * SS;
    const ushort* kpe_b = kvbf + (size_t)b * SS * 576 + 512;
    const int* mrow = mask + b * SS;
    ushort* Ptw = Pt + w * 16 * PTL;

    // Q B-frags: rows s0+16w..+15 (n = lane&15), 6 k-chunks of 32 over 192 dims
    bf16x8 qf[6];
    {
        const ushort* qbase = qbuf + ((size_t)(b * SS) + s0 + 16 * w + l15) * 3072 + h * QKH_D + q * 8;
#pragma unroll
        for (int k = 0; k < 6; k++) qf[k] = *(const bf16x8*)(qbase + k * 32);
    }

    f32x4 Oacc[8];   // O^T: rows d = 16nt+4q+r, col s = l15
#pragma unroll
    for (int nt = 0; nt < 8; nt++) Oacc[nt] = (f32x4){0.f, 0.f, 0.f, 0.f};
    float m_i = -3e38f, l_i = 0.f;
    const int my_s = s0 + 16 * w + l15;

    for (int st = t0s; st < t1s; st++) {
        const int t0 = st * 64;
        // ---- stage K-tile (24 groups) + V^T tile (16 groups); wave w: 6 K + 4 V ----
#pragma unroll
        for (int i = 0; i < 6; i++) {
            int g = 6 * w + i;
            int rg = g & 7, cg = g >> 3;
            int row = rg * 8 + r7;
            int chl = c7 ^ r7;
            const ushort* src = (cg < 2)
                ? Kf_bh + (size_t)(t0 + row) * NOPE_D + (cg * 8 + chl) * 8
                : kpe_b + (size_t)(t0 + row) * 576 + chl * 8;
            gload_lds16(src, Kt + g * 512 + lane * 8);
        }
#pragma unroll
        for (int i = 0; i < 4; i++) {
            int g = 4 * w + i;                  // d-group 0..15
            int d = g * 8 + r7;
            gload_lds16(VT_bh + (size_t)d * SS + t0 + ((c7 ^ r7) << 3),
                        Vt + g * 512 + lane * 8);
        }
        __syncthreads();
        // ---- scores S^T(64 t x 16 s): sa[c] rows t=16c+4q+r, col s=l15 ----
        f32x4 sa[4];
#pragma unroll
        for (int c = 0; c < 4; c++) sa[c] = (f32x4){0.f, 0.f, 0.f, 0.f};
#pragma unroll
        for (int k = 0; k < 6; k++) {
#pragma unroll
            for (int c = 0; c < 4; c++) {
                bf16x8 kb = *(const bf16x8*)(Kt + ktidx(16 * c + l15, 4 * k + q));
                sa[c] = __builtin_amdgcn_mfma_f32_16x16x32_bf16(kb, qf[k], sa[c], 0, 0, 0);
            }
        }
        // wait: kb rows use l15 as t here?  No — A-frag m = lane&15 = t-row.
        // sa[c] holds S^T for t = 16c + 4q + r ... computed with kb read at
        // row 16c + l15: A[m=lane&15] = t = 16c + l15 is the OPERAND layout;
        // output D rows are m = 16c-tile's 4q+r.  Consistent: one MFMA per
        // 16-t tile c.  (operand row uses l15, output row uses 4q+r.)
        // ---- softmax: in-register over t, 2 shfl over s-duplicated quads ----
        float sc[4][4];
        float mx = -3e38f;
#pragma unroll
        for (int c = 0; c < 4; c++) {
            int4 mv4 = *(const int4*)&mrow[t0 + 16 * c + 4 * q];
#pragma unroll
            for (int r = 0; r < 4; r++) {
                int t = t0 + 16 * c + 4 * q + r;
                float v = sa[c][r] * SCL;
                int mvr = (&mv4.x)[r];
                if (t > my_s || mvr == 0) v = -1e30f;
                sc[c][r] = v;
                mx = fmaxf(mx, v);
            }
        }
        mx = fmaxf(mx, __shfl_xor(mx, 16));
        mx = fmaxf(mx, __shfl_xor(mx, 32));
        float mn = fmaxf(m_i, mx);
        float alpha = exp2f(m_i - mn);
        m_i = mn;
        float ps = 0.f;
#pragma unroll
        for (int c = 0; c < 4; c++) {
            ushort4 pk;
#pragma unroll
            for (int r = 0; r < 4; r++) {
                float p = (sc[c][r] <= -1e29f) ? 0.f : exp2f(sc[c][r] - mn);
                ps += p;
                (&pk.x)[r] = f2bf(p);
            }
            *(ushort4*)(Ptw + l15 * PTL + 16 * c + 4 * q) = pk;
        }
        ps += __shfl_xor(ps, 16);
        ps += __shfl_xor(ps, 32);
        l_i = l_i * alpha + ps;
        // ---- rescale O^T (scalar per lane) ----
#pragma unroll
        for (int nt = 0; nt < 8; nt++) {
            Oacc[nt][0] *= alpha; Oacc[nt][1] *= alpha;
            Oacc[nt][2] *= alpha; Oacc[nt][3] *= alpha;
        }
        // ---- PV: O^T(128 d x 16 s) += V^T(LDS) @ P^T(wave LDS) ----
        bf16x8 pb[2];
#pragma unroll
        for (int kt = 0; kt < 2; kt++)
            pb[kt] = *(const bf16x8*)(Ptw + l15 * PTL + kt * 32 + q * 8);
#pragma unroll
        for (int nt = 0; nt < 8; nt++) {
#pragma unroll
            for (int kt = 0; kt < 2; kt++) {
                bf16x8 vf = *(const bf16x8*)(Vt + vtidx(16 * nt + l15, kt * 4 + q));
                Oacc[nt] = __builtin_amdgcn_mfma_f32_16x16x32_bf16(vf, pb[kt], Oacc[nt], 0, 0, 0);
            }
        }
        __syncthreads();   // protect Kt/Vt for next step
    }

    // ---- epilogue (intra-wave; O^T rows d = 16nt+4q+r, col s = l15) ----
    float lv = (l_i > 0.f) ? 1.f / l_i : 0.f;

    if (!partial) {
        ushort* orow = o_heads + (size_t)(b * SS + my_s) * 2048 + h * VD_D;
#pragma unroll
        for (int nt = 0; nt < 8; nt++) {
            ushort4 pk;
            pk.x = f2bf(Oacc[nt][0] * lv); pk.y = f2bf(Oacc[nt][1] * lv);
            pk.z = f2bf(Oacc[nt][2] * lv); pk.w = f2bf(Oacc[nt][3] * lv);
            *(ushort4*)(orow + 16 * nt + 4 * q) = pk;
        }
    } else {
        const int sp = (t0s != 0);
        const int p = bh * 26 + (qt - 19) * 2 + sp;
        const int rl = 16 * w + l15;
        ushort* prow = Opart + ((size_t)p * 64 + rl) * 128;
#pragma unroll
        for (int nt = 0; nt < 8; nt++) {
            ushort4 pk;
            pk.x = f2bf(Oacc[nt][0] * lv); pk.y = f2bf(Oacc[nt][1] * lv);
            pk.z = f2bf(Oacc[nt][2] * lv); pk.w = f2bf(Oacc[nt][3] * lv);
            *(ushort4*)(prow + 16 * nt + 4 * q) = pk;
        }
        if (lane < 16)
            mlbuf[p * 64 + rl] = make_float2(m_i, l_i);
    }
}

// ---------------------------------------------------------------------------
// Merge span0/span1 partials for qt>=19.  grid 416 (= 32bh x 13qt) x 256.
// ---------------------------------------------------------------------------
__launch_bounds__(256)
__global__ void attn_merge(const ushort* __restrict__ Opart, const float2* __restrict__ mlbuf,
                           ushort* __restrict__ o_heads)
{
    int bh = blockIdx.x & 31, qi = blockIdx.x >> 5;
    int b = bh >> 4, h = bh & 15;
    int qt = 19 + qi;
    int t = threadIdx.x;
    int row = t >> 2, dbase = (t & 3) * 32;
    int p0 = bh * 26 + qi * 2, p1 = p0 + 1;
    float2 ml0 = mlbuf[p0 * 64 + row], ml1 = mlbuf[p1 * 64 + row];
    float M = fmaxf(ml0.x, ml1.x);
    float w0 = (ml0.y > 0.f) ? exp2f(ml0.x - M) * ml0.y : 0.f;
    float w1 = (ml1.y > 0.f) ? exp2f(ml1.x - M) * ml1.y : 0.f;
    float den = w0 + w1;
    float inv = (den > 0.f) ? 1.f / den : 0.f;
    w0 *= inv; w1 *= inv;
    int s = qt * 64 + row;
    const ushort* O0 = Opart + ((size_t)p0 * 64 + row) * 128 + dbase;
    const ushort* O1 = Opart + ((size_t)p1 * 64 + row) * 128 + dbase;
    ushort* dst = o_heads + (size_t)(b * SS + s) * 2048 + h * VD_D + dbase;
#pragma unroll
    for (int c = 0; c < 32; c += 8) {
        bf16x8 a = *(const bf16x8*)(O0 + c);
        bf16x8 bb = *(const bf16x8*)(O1 + c);
        bf16x8 o;
#pragma unroll
        for (int j = 0; j < 8; j++)
            o[j] = (short)f2bf(w0 * bf2f((unsigned short)a[j]) + w1 * bf2f((unsigned short)bb[j]));
        *(bf16x8*)(dst + c) = o;
    }
}

extern "C" void kernel_launch(void* const* d_in, const int* in_sizes, int n_in,
                              void* d_out, int out_size, void* d_ws, size_t ws_size,
                              hipStream_t stream)
{
    const float* x        = (const float*)d_in[0];
    const int*   mask     = (const int*)d_in[1];
    const float* wq_a_w   = (const float*)d_in[2];
    const float* wq_a_b   = (const float*)d_in[3];
    const float* q_norm_w = (const float*)d_in[4];
    const float* wq_b_w   = (const float*)d_in[5];
    const float* wq_b_b   = (const float*)d_in[6];
    const float* wkv_a_w  = (const float*)d_in[7];
    const float* wkv_a_b  = (const float*)d_in[8];
    const float* kv_norm_w= (const float*)d_in[9];
    const float* wkv_b_w  = (const float*)d_in[10];
    const float* wo_w     = (const float*)d_in[11];
    const float* wo_b     = (const float*)d_in[12];
    float* out = (float*)d_out;

    // Workspace (peak 102,662,144 B) — layout identical to R8
    char* W = (char*)d_ws;
    ushort* wo_bf    = (ushort*)(W + 0);
    ushort* qbuf     = (ushort*)(W + 8388608);
    ushort* wq_b_bf  = (ushort*)(W + 33554432);
    ushort* Kf       = (ushort*)(W + 33554432);
    ushort* wq_a_bf  = (ushort*)(W + 42991616);
    ushort* kvfull_bf= (ushort*)(W + 42991616);
    ushort* x_bf     = (ushort*)(W + 50331648);
    ushort* VT       = (ushort*)(W + 50331648);
    ushort* q_a_bf   = (ushort*)(W + 67108864);
    ushort* o_heads  = (ushort*)(W + 67108864);
    ushort* wkv_a_bf = (ushort*)(W + 79691776);
    ushort* wkv_b_bf = (ushort*)(W + 83886080);
    ushort* Opart    = (ushort*)(W + 83886080);
    float2* mlbuf    = (float2*)(W + 97517568);
    ushort* kvbf     = (ushort*)(W + 97943552);

    // 0. all f32->bf16 converts, one launch
    conv6<<<4096, 256, 0, stream>>>(
        x, x_bf, MROWS * HH / 4,
        wq_a_w, wq_a_bf, QLL * HH / 4,
        wq_b_w, wq_b_bf, 3072 * QLL / 4,
        wkv_a_w, wkv_a_bf, 576 * HH / 4,
        wkv_b_w, wkv_b_bf, NHH * 256 * 512 / 4,
        wo_w, wo_bf, HH * 2048 / 4);

    // 1. q_a = x @ wq_a^T + b  -> bf16
    gemm_bf<ushort><<<dim3(QLL/128, MROWS/128, 1), 256, 0, stream>>>(
        x_bf, HH, 0, 0, wq_a_bf, HH, 0, 0, wq_a_b, q_a_bf, QLL, 0, 0, MROWS, QLL, HH);
    // 2. rms_norm in place (bf16)
    rmsnorm_bf16<<<MROWS, 256, 0, stream>>>(q_a_bf, q_norm_w, QLL);
    // 3. q = q_a @ wq_b^T + b -> qbuf bf16
    gemm_bf<ushort><<<dim3(3072/128, MROWS/128, 1), 256, 0, stream>>>(
        q_a_bf, QLL, 0, 0, wq_b_bf, QLL, 0, 0, wq_b_b, qbuf, 3072, 0, 0, MROWS, 3072, QLL);
    // 4. kv_full = x @ wkv_a^T + b -> bf16 (N=576 guarded)
    gemm_bf<ushort><<<dim3(5, MROWS/128, 1), 256, 0, stream>>>(
        x_bf, HH, 0, 0, wkv_a_bf, HH, 0, 0, wkv_a_b, kvfull_bf, 576, 0, 0, MROWS, 576, HH);
    // 5. finalize kv (rms + rope) -> kvbf
    finalize_kv<<<MROWS, 256, 0, stream>>>(kvfull_bf, kv_norm_w, kvbf);
    // 6. rope q_pe in place on qbuf
    rope_q_kernel<<<dim3(MROWS, 4), 256, 0, stream>>>(qbuf);
    // 7. Kf[b,h] = kv_lat @ W_UK[h]^T  (nope only; M=2048,N=128,K=512, z=32)
    gemm_bf<ushort><<<dim3(1, SS/128, 32), 256, 0, stream>>>(
        kvbf, 576, (size_t)SS * 576, 0,
        wkv_b_bf, 512, 0, (size_t)256 * 512,
        nullptr, Kf, NOPE_D, (size_t)NHH * SS * NOPE_D, (size_t)SS * NOPE_D,
        SS, NOPE_D, 512);
    // 9. VT[b,h] = W_UV[h] @ kv_lat^T  (M=128,N=2048,K=512, z=32)
    gemm_bf<ushort><<<dim3(SS/128, 1, 32), 256, 0, stream>>>(
        wkv_b_bf + (size_t)128 * 512, 512, 0, (size_t)256 * 512,
        kvbf, 576, (size_t)SS * 576, 0,
        nullptr, VT, SS, (size_t)NHH * VD_D * SS, (size_t)VD_D * SS,
        VD_D, SS, 512);
    // 10. split-K MFMA flash attention (1440 blocks) + merge
    attn_mfma<<<NJOB * 32, 256, 0, stream>>>(qbuf, Kf, kvbf, VT, mask, o_heads, Opart, mlbuf);
    attn_merge<<<13 * 32, 256, 0, stream>>>(Opart, mlbuf, o_heads);
    // 12. out = o_heads @ wo^T + b
    gemm_bf<float><<<dim3(HH/128, MROWS/128, 1), 256, 0, stream>>>(
        o_heads, NHH * VD_D, 0, 0, wo_bf, NHH * VD_D, 0, 0, wo_b, out, HH, 0, 0,
        MROWS, HH, NHH * VD_D);
}